// Round 12
// baseline (94.856 us; speedup 1.0000x reference)
//
#include <hip/hip_runtime.h>
#include <hip/hip_bf16.h>
#include <stdint.h>

#define MDIM 1024
#define NDIM 4096
#define KDIM 4096

#define BM 128
#define BN 128

typedef __attribute__((ext_vector_type(4))) float f32x4;
typedef __attribute__((ext_vector_type(4))) float float4v;
typedef __attribute__((ext_vector_type(4))) int int4v;
typedef __attribute__((ext_vector_type(4))) unsigned int uint4v;
typedef __attribute__((ext_vector_type(8))) short short8;

#define GLOBAL_AS __attribute__((address_space(1)))
#define LDS_AS __attribute__((address_space(3)))

// Hardened barrier (rule #18): race-free rounds 5-11. Used ONLY in the
// end-of-kernel reduction now — the K-loop has no barriers at all.
#define HARD_BARRIER() do {                               \
    __builtin_amdgcn_sched_barrier(0);                    \
    asm volatile("s_waitcnt lgkmcnt(0)" ::: "memory");    \
    __builtin_amdgcn_s_barrier();                         \
    asm volatile("" ::: "memory");                        \
    __builtin_amdgcn_sched_barrier(0);                    \
} while (0)

__device__ __constant__ float c_nf4[16] = {
    -1.0f, -0.6961928009986877f, -0.5250730514526367f, -0.39491748809814453f,
    -0.28444138169288635f, -0.18477343022823334f, -0.09105003625154495f, 0.0f,
    0.07958029955625534f, 0.16093020141124725f, 0.24611230194568634f,
    0.33791524171829224f, 0.44070982933044434f, 0.5626170039176941f,
    0.7229568362236023f, 1.0f};

__device__ __forceinline__ unsigned bf16_rne(float f) {
    unsigned u = __float_as_uint(f);
    return (u + 0x7fffu + ((u >> 16) & 1u)) >> 16;
}

// ---------------------------------------------------------------------------
// Prep: dequant/convert AND write in MFMA-fragment-major order.
// 16B unit (8 bf16) for element block (row, k8):  (k = k8*8)
//   r16 = row>>4, r = row&15, kc = k8>>2 (32-k chunk), hi = k8&3
//   unit index = (r16*128 + kc)*64 + hi*16 + r      [lane = hi*16 + r]
// so GEMM's frag load (r16, kc) is one perfectly-coalesced 1KB dwordx4 load:
// lane l -> row r16*16+(l&15), k = kc*32+(l>>4)*8..+8 — exactly the
// 16x16x32 MFMA operand layout proven in rounds 2-11.
// ---------------------------------------------------------------------------
#define W_BLOCKS ((NDIM * KDIM) / (256 * 8))   // 8192
#define X_BLOCKS ((MDIM * KDIM) / (256 * 8))   // 2048

__global__ __launch_bounds__(256) void prep_kernel(
    const float* __restrict__ x, const float* __restrict__ w0,
    const int* __restrict__ nf4_idx, const float* __restrict__ scale_p,
    const float* __restrict__ zp_p, __hip_bfloat16* __restrict__ Wc,
    __hip_bfloat16* __restrict__ xb)
{
    const int lane = threadIdx.x & 63;
    if (blockIdx.x < W_BLOCKS) {
        const float scale = scale_p[0];
        const float zp = zp_p[0];
        const int tab = __float_as_int(c_nf4[lane & 15] * scale + zp);
        const size_t base = ((size_t)blockIdx.x * 256 + threadIdx.x) * 8;
        // fragment-major output unit
        const int row = (int)(base >> 12);          // /KDIM
        const int k8 = (int)((base >> 3) & 511);
        const int kc = k8 >> 2, hi = k8 & 3;
        const size_t unit =
            ((size_t)(row >> 4) * 128 + kc) * 64 + hi * 16 + (row & 15);
        int4v i0 = *(const int4v*)(nf4_idx + base);
        int4v i1 = *(const int4v*)(nf4_idx + base + 4);
        float4v w_0 = *(const float4v*)(w0 + base);
        float4v w_1 = *(const float4v*)(w0 + base + 4);
        unsigned r[8];
#pragma unroll
        for (int j = 0; j < 4; j++) {
            float q = __int_as_float(__builtin_amdgcn_ds_bpermute(i0[j] * 4, tab));
            r[j] = bf16_rne(w_0[j] + q);
        }
#pragma unroll
        for (int j = 0; j < 4; j++) {
            float q = __int_as_float(__builtin_amdgcn_ds_bpermute(i1[j] * 4, tab));
            r[4 + j] = bf16_rne(w_1[j] + q);
        }
        uint4v st;
        st.x = r[0] | (r[1] << 16);
        st.y = r[2] | (r[3] << 16);
        st.z = r[4] | (r[5] << 16);
        st.w = r[6] | (r[7] << 16);
        *(uint4v*)((unsigned short*)Wc + unit * 8) = st;
    } else {
        const size_t base = ((size_t)(blockIdx.x - W_BLOCKS) * 256 + threadIdx.x) * 8;
        const int row = (int)(base >> 12);
        const int k8 = (int)((base >> 3) & 511);
        const int kc = k8 >> 2, hi = k8 & 3;
        const size_t unit =
            ((size_t)(row >> 4) * 128 + kc) * 64 + hi * 16 + (row & 15);
        float4v a0 = *(const float4v*)(x + base);
        float4v a1 = *(const float4v*)(x + base + 4);
        uint4v st;
        st.x = bf16_rne(a0[0]) | (bf16_rne(a0[1]) << 16);
        st.y = bf16_rne(a0[2]) | (bf16_rne(a0[3]) << 16);
        st.z = bf16_rne(a1[0]) | (bf16_rne(a1[1]) << 16);
        st.w = bf16_rne(a1[2]) | (bf16_rne(a1[3]) << 16);
        *(uint4v*)((unsigned short*)xb + unit * 8) = st;
    }
}

// ---------------------------------------------------------------------------
// LDS-free GEMM: fragments loaded register-direct from fragment-major ws.
// 128x128 block, 8 waves 2m x 2n x 2k (wave = 64x64 over its K-half).
// Per wave-step: 8 coalesced 1KB global loads -> 16 MFMA. NO LDS staging,
// NO barriers, NO waitcnt asm in the loop — waves run free; 4-deep named
// register pipeline (rule #20: all indices compile-time). End: round-10
// cross-wk LDS reduction (one barrier total).
// XCD remap keeps each XCD's B panel at 4 MB (L2-resident).
// ---------------------------------------------------------------------------
__global__ __launch_bounds__(512, 2) void gemm_kernel(
    const __hip_bfloat16* __restrict__ A,   // xb fragment-major
    const __hip_bfloat16* __restrict__ B,   // Wc fragment-major
    float* __restrict__ C)                  // [MDIM][NDIM]
{
    __shared__ float red[4 * 4096];          // 64 KiB, reduction only

    const int tid = threadIdx.x;
    const int lane = tid & 63;
    const int w = tid >> 6;          // wave 0..7
    const int wr = w >> 2;           // 0..1 -> m-offset 64
    const int wc = (w >> 1) & 1;     // 0..1 -> n-offset 64
    const int wk = w & 1;            // 0..1 -> K-half

    const int bid = blockIdx.x;
    const int orig = (bid & 7) * 32 + (bid >> 3);
    const int mtile = orig & 7;      // 0..7
    const int ntile = orig >> 3;     // 0..31

    const short8* Af = (const short8*)A;
    const short8* Bf = (const short8*)B;

    // fragment unit bases: frag (r16, kc) at unit (r16*128 + kc)*64 + lane
    int au[4], bu[4];
#pragma unroll
    for (int m = 0; m < 4; m++)
        au[m] = ((mtile * 8 + wr * 4 + m) * 128 + wk * 64) * 64 + lane;
#pragma unroll
    for (int n = 0; n < 4; n++)
        bu[n] = ((ntile * 8 + wc * 4 + n) * 128 + wk * 64) * 64 + lane;

    f32x4 acc[4][4] = {};
    short8 fa0[4], fb0[4], fa1[4], fb1[4], fa2[4], fb2[4], fa3[4], fb3[4];

#define LOADF(fa, fb, t) do {                                                 \
    _Pragma("unroll")                                                         \
    for (int m = 0; m < 4; m++) fa[m] = Af[au[m] + (t) * 64];                 \
    _Pragma("unroll")                                                         \
    for (int n = 0; n < 4; n++) fb[n] = Bf[bu[n] + (t) * 64];                 \
} while (0)

#define MF(fa, fb) do {                                                       \
    _Pragma("unroll")                                                         \
    for (int m = 0; m < 4; m++)                                               \
        _Pragma("unroll")                                                     \
        for (int n = 0; n < 4; n++)                                           \
            acc[m][n] = __builtin_amdgcn_mfma_f32_16x16x32_bf16(              \
                fa[m], fb[n], acc[m][n], 0, 0, 0);                            \
} while (0)

    // 64 K-steps (this wave's K-half), 4-deep register pipeline.
    LOADF(fa0, fb0, 0);
    LOADF(fa1, fb1, 1);
    LOADF(fa2, fb2, 2);
    for (int t = 0; t < 64; t += 4) {
        LOADF(fa3, fb3, t + 3);
        MF(fa0, fb0);
        if (t + 4 < 64) LOADF(fa0, fb0, t + 4);
        MF(fa1, fb1);
        if (t + 5 < 64) LOADF(fa1, fb1, t + 5);
        MF(fa2, fb2);
        if (t + 6 < 64) LOADF(fa2, fb2, t + 6);
        MF(fa3, fb3);
    }

    // --- cross-wk reduction through LDS (round-10 proven layout) ---
    const int pair = wr * 2 + wc;            // 0..3
    if (wk == 1) {
#pragma unroll
        for (int m = 0; m < 4; m++) {
#pragma unroll
            for (int n = 0; n < 4; n++) {
                *(f32x4*)&red[pair * 4096 + (m * 4 + n) * 256 + lane * 4] =
                    acc[m][n];
            }
        }
    }
    HARD_BARRIER();   // lgkmcnt(0) drain -> writes visible to wk==0 waves
    if (wk == 0) {
        // epilogue: C/D layout col = lane&15, row = (lane>>4)*4 + r
        const int rbase = mtile * BM + wr * 64 + ((lane >> 4) << 2);
        const int cbase = ntile * BN + wc * 64 + (lane & 15);
#pragma unroll
        for (int m = 0; m < 4; m++) {
#pragma unroll
            for (int n = 0; n < 4; n++) {
                f32x4 other =
                    *(const f32x4*)&red[pair * 4096 + (m * 4 + n) * 256 + lane * 4];
                f32x4 v = acc[m][n] + other;
#pragma unroll
                for (int r = 0; r < 4; r++) {
                    C[(size_t)(rbase + m * 16 + r) * NDIM + cbase + n * 16] = v[r];
                }
            }
        }
    }
#undef LOADF
#undef MF
}

// ---------------------------------------------------------------------------
// Fallback (only if ws too small): textbook fp32 tiled GEMM with inline dequant
// ---------------------------------------------------------------------------
__global__ void fallback_kernel(const float* __restrict__ x,
                                const float* __restrict__ w0,
                                const int* __restrict__ nf4_idx,
                                const float* __restrict__ sp,
                                const float* __restrict__ zpp,
                                float* __restrict__ out)
{
    __shared__ float As[16][16], Bs[16][17];
    const int tx = threadIdx.x, ty = threadIdx.y;
    const int n0 = blockIdx.x * 16, m0 = blockIdx.y * 16;
    const float s = sp[0], zp = zpp[0];
    float acc = 0.0f;
    for (int k0 = 0; k0 < KDIM; k0 += 16) {
        As[ty][tx] = x[(size_t)(m0 + ty) * KDIM + k0 + tx];
        int id = nf4_idx[(size_t)(n0 + ty) * KDIM + k0 + tx];
        Bs[ty][tx] = w0[(size_t)(n0 + ty) * KDIM + k0 + tx] + c_nf4[id] * s + zp;
        __syncthreads();
#pragma unroll
        for (int j = 0; j < 16; j++) acc += As[ty][j] * Bs[tx][j];
        __syncthreads();
    }
    out[(size_t)(m0 + ty) * NDIM + n0 + tx] = acc;
}

extern "C" void kernel_launch(void* const* d_in, const int* in_sizes, int n_in,
                              void* d_out, int out_size, void* d_ws, size_t ws_size,
                              hipStream_t stream) {
    const float* x = (const float*)d_in[0];
    const float* w0 = (const float*)d_in[1];
    const int* nf4_idx = (const int*)d_in[2];
    const float* scale = (const float*)d_in[3];
    const float* zp = (const float*)d_in[4];
    float* out = (float*)d_out;

    const size_t wc_bytes = (size_t)NDIM * KDIM * 2;       // 33,554,432
    const size_t xb_bytes = (size_t)MDIM * KDIM * 2;       //  8,388,608

    if (ws_size >= wc_bytes + xb_bytes) {
        __hip_bfloat16* Wc = (__hip_bfloat16*)d_ws;
        __hip_bfloat16* xb = (__hip_bfloat16*)((char*)d_ws + wc_bytes);
        prep_kernel<<<W_BLOCKS + X_BLOCKS, 256, 0, stream>>>(
            x, w0, nf4_idx, scale, zp, Wc, xb);
        gemm_kernel<<<(MDIM / BM) * (NDIM / BN), 512, 0, stream>>>(xb, Wc, out);
    } else {
        fallback_kernel<<<dim3(NDIM / 16, MDIM / 16), dim3(16, 16), 0, stream>>>(
            x, w0, nf4_idx, scale, zp, out);
    }
}

// Round 13
// 66.524 us; speedup vs baseline: 1.4259x; 1.4259x over previous
//
#include <hip/hip_runtime.h>
#include <hip/hip_bf16.h>
#include <stdint.h>

#define MDIM 1024
#define NDIM 4096
#define KDIM 4096

#define BM 128
#define BN 128
#define BK 64

typedef __attribute__((ext_vector_type(4))) float f32x4;
typedef __attribute__((ext_vector_type(4))) float float4v;
typedef __attribute__((ext_vector_type(4))) int int4v;
typedef __attribute__((ext_vector_type(4))) unsigned int uint4v;
typedef __attribute__((ext_vector_type(8))) short short8;

#define GLOBAL_AS __attribute__((address_space(1)))
#define LDS_AS __attribute__((address_space(3)))

// Hardened barrier (rule #18): sched_barrier(0) on BOTH sides + lgkmcnt(0)
// drain. Race-free across rounds 5-11 benches (cold + L2-warm replay).
#define HARD_BARRIER() do {                               \
    __builtin_amdgcn_sched_barrier(0);                    \
    asm volatile("s_waitcnt lgkmcnt(0)" ::: "memory");    \
    __builtin_amdgcn_s_barrier();                         \
    asm volatile("" ::: "memory");                        \
    __builtin_amdgcn_sched_barrier(0);                    \
} while (0)

__device__ __constant__ float c_nf4[16] = {
    -1.0f, -0.6961928009986877f, -0.5250730514526367f, -0.39491748809814453f,
    -0.28444138169288635f, -0.18477343022823334f, -0.09105003625154495f, 0.0f,
    0.07958029955625534f, 0.16093020141124725f, 0.24611230194568634f,
    0.33791524171829224f, 0.44070982933044434f, 0.5626170039176941f,
    0.7229568362236023f, 1.0f};

__device__ __forceinline__ unsigned bf16_rne(float f) {
    unsigned u = __float_as_uint(f);
    return (u + 0x7fffu + ((u >> 16) & 1u)) >> 16;
}

// ---------------------------------------------------------------------------
// Prep: Wc = bf16(w0 + NF4[idx]*scale + zp); xb = bf16(x)
// Row-major contiguous output (round 12 showed fragment-major scatter
// doubles HBM write traffic — write coalescing is binding).
// ---------------------------------------------------------------------------
#define W_BLOCKS ((NDIM * KDIM) / (256 * 8))   // 8192
#define X_BLOCKS ((MDIM * KDIM) / (256 * 8))   // 2048

__global__ __launch_bounds__(256) void prep_kernel(
    const float* __restrict__ x, const float* __restrict__ w0,
    const int* __restrict__ nf4_idx, const float* __restrict__ scale_p,
    const float* __restrict__ zp_p, __hip_bfloat16* __restrict__ Wc,
    __hip_bfloat16* __restrict__ xb)
{
    const int lane = threadIdx.x & 63;
    if (blockIdx.x < W_BLOCKS) {
        const float scale = scale_p[0];
        const float zp = zp_p[0];
        const int tab = __float_as_int(c_nf4[lane & 15] * scale + zp);
        const size_t base = ((size_t)blockIdx.x * 256 + threadIdx.x) * 8;
        int4v i0 = *(const int4v*)(nf4_idx + base);
        int4v i1 = *(const int4v*)(nf4_idx + base + 4);
        float4v w_0 = *(const float4v*)(w0 + base);
        float4v w_1 = *(const float4v*)(w0 + base + 4);
        unsigned r[8];
#pragma unroll
        for (int j = 0; j < 4; j++) {
            float q = __int_as_float(__builtin_amdgcn_ds_bpermute(i0[j] * 4, tab));
            r[j] = bf16_rne(w_0[j] + q);
        }
#pragma unroll
        for (int j = 0; j < 4; j++) {
            float q = __int_as_float(__builtin_amdgcn_ds_bpermute(i1[j] * 4, tab));
            r[4 + j] = bf16_rne(w_1[j] + q);
        }
        uint4v st;
        st.x = r[0] | (r[1] << 16);
        st.y = r[2] | (r[3] << 16);
        st.z = r[4] | (r[5] << 16);
        st.w = r[6] | (r[7] << 16);
        *(uint4v*)((unsigned short*)Wc + base) = st;
    } else {
        const size_t base = ((size_t)(blockIdx.x - W_BLOCKS) * 256 + threadIdx.x) * 8;
        float4v a0 = *(const float4v*)(x + base);
        float4v a1 = *(const float4v*)(x + base + 4);
        uint4v st;
        st.x = bf16_rne(a0[0]) | (bf16_rne(a0[1]) << 16);
        st.y = bf16_rne(a0[2]) | (bf16_rne(a0[3]) << 16);
        st.z = bf16_rne(a1[0]) | (bf16_rne(a1[1]) << 16);
        st.w = bf16_rne(a1[2]) | (bf16_rne(a1[3]) << 16);
        *(uint4v*)((unsigned short*)xb + base) = st;
    }
}

// ---------------------------------------------------------------------------
// GEMM (round-10 best, byte-identical): C[m][n] = sum_k A[m][k] * B[n][k]
// 128x128 tile, BK=64, 4 LDS buffers, ONE barrier/K-step, pf distance 2,
// counted vmcnt(8), XOR swizzle via pre-swizzled global source, XCD remap,
// LDS-minimal wave split 2m x 2n x 2k + cross-wk LDS reduction.
// ---------------------------------------------------------------------------
__global__ __launch_bounds__(512) void gemm_kernel(
    const __hip_bfloat16* __restrict__ A,   // [MDIM][KDIM]
    const __hip_bfloat16* __restrict__ B,   // [NDIM][KDIM]
    float* __restrict__ C)                  // [MDIM][NDIM]
{
    __shared__ __hip_bfloat16 sm[4][2][BM * BK];  // 128 KiB

    const int tid = threadIdx.x;
    const int lane = tid & 63;
    const int w = tid >> 6;          // wave 0..7
    const int wr = w >> 2;           // 0..1 -> m-offset 64
    const int wc = (w >> 1) & 1;     // 0..1 -> n-offset 64
    const int wk = w & 1;            // 0..1 -> k-half within BK

    // XCD remap: orig = (bid%8)*32 + bid/8 -> XCD x owns ntiles [x*4, x*4+4)
    const int bid = blockIdx.x;
    const int orig = (bid & 7) * 32 + (bid >> 3);
    const int mtile = orig & 7;      // 0..7
    const int ntile = orig >> 3;     // 0..31

    const int s_subrow = lane >> 3;
    const int s_chunkpos = lane & 7;
    int s_row[2], s_goff[2];
#pragma unroll
    for (int j = 0; j < 2; j++) {
        int row = w * 16 + j * 8 + s_subrow;
        s_row[j] = row;
        s_goff[j] = (s_chunkpos ^ (row & 7)) * 8;  // content chunk for slot
    }

#define STAGE(buf, kt) do {                                                        \
    _Pragma("unroll")                                                              \
    for (int j = 0; j < 2; j++) {                                                  \
        const __hip_bfloat16* ga = A + (size_t)(mtile * BM + s_row[j]) * KDIM      \
                                     + (kt) * BK + s_goff[j];                      \
        __builtin_amdgcn_global_load_lds((const GLOBAL_AS void*)ga,                \
            (LDS_AS void*)&sm[buf][0][(w * 16 + j * 8) * BK], 16, 0, 0);           \
        const __hip_bfloat16* gb = B + (size_t)(ntile * BN + s_row[j]) * KDIM      \
                                     + (kt) * BK + s_goff[j];                      \
        __builtin_amdgcn_global_load_lds((const GLOBAL_AS void*)gb,                \
            (LDS_AS void*)&sm[buf][1][(w * 16 + j * 8) * BK], 16, 0, 0);           \
    }                                                                              \
} while (0)

    // 16x16x32 frag at k-chunk = wk*32: lane holds [row][k=(lane>>4)*8 ..+8]
    int a_off[4], b_off[4];
#pragma unroll
    for (int m = 0; m < 4; m++) {
        int row = wr * 64 + m * 16 + (lane & 15);
        int c = wk * 4 + (lane >> 4);
        a_off[m] = row * BK + (c ^ (row & 7)) * 8;
    }
#pragma unroll
    for (int n = 0; n < 4; n++) {
        int row = wc * 64 + n * 16 + (lane & 15);
        int c = wk * 4 + (lane >> 4);
        b_off[n] = row * BK + (c ^ (row & 7)) * 8;
    }

    f32x4 acc[4][4] = {};

#define COMPUTE(buf) do {                                                          \
    short8 af[4], bfv[4];                                                          \
    _Pragma("unroll")                                                              \
    for (int m = 0; m < 4; m++)                                                    \
        af[m] = *(const short8*)&sm[buf][0][a_off[m]];                             \
    _Pragma("unroll")                                                              \
    for (int n = 0; n < 4; n++)                                                    \
        bfv[n] = *(const short8*)&sm[buf][1][b_off[n]];                            \
    _Pragma("unroll")                                                              \
    for (int m = 0; m < 4; m++)                                                    \
        _Pragma("unroll")                                                          \
        for (int n = 0; n < 4; n++)                                                \
            acc[m][n] = __builtin_amdgcn_mfma_f32_16x16x32_bf16(                   \
                af[m], bfv[n], acc[m][n], 0, 0, 0);                                \
} while (0)

    const int NT = KDIM / BK;  // 64 (NT % 4 == 0)
    STAGE(0, 0);
    STAGE(1, 1);

    for (int t = 0; t < NT; t++) {
        const int cur = t & 3;
        // STAGE(t+2) writes (t+2)%4; concurrent readers are at (t-1)%4 and
        // t%4 -> WAR distances 3 and 2, never 0: no trailing barrier needed.
        if (t + 2 < NT) {
            STAGE((t + 2) & 3, t + 2);
            asm volatile("s_waitcnt vmcnt(8)" ::: "memory");
        } else if (t + 1 < NT) {
            asm volatile("s_waitcnt vmcnt(4)" ::: "memory");
        } else {
            asm volatile("s_waitcnt vmcnt(0)" ::: "memory");
        }
        HARD_BARRIER();        // single barrier: every wave's stage(t) landed
        COMPUTE(cur);          // WAR protection for restage = buffer distance
    }

    // --- cross-wk reduction through LDS ---
    HARD_BARRIER();
    float* red = (float*)&sm[0][0][0];
    const int pair = wr * 2 + wc;            // 0..3
    if (wk == 1) {
#pragma unroll
        for (int m = 0; m < 4; m++) {
#pragma unroll
            for (int n = 0; n < 4; n++) {
                *(f32x4*)&red[pair * 4096 + (m * 4 + n) * 256 + lane * 4] =
                    acc[m][n];
            }
        }
    }
    HARD_BARRIER();   // includes lgkmcnt(0) drain -> writes visible
    if (wk == 0) {
        const int rbase = mtile * BM + wr * 64 + ((lane >> 4) << 2);
        const int cbase = ntile * BN + wc * 64 + (lane & 15);
#pragma unroll
        for (int m = 0; m < 4; m++) {
#pragma unroll
            for (int n = 0; n < 4; n++) {
                f32x4 other =
                    *(const f32x4*)&red[pair * 4096 + (m * 4 + n) * 256 + lane * 4];
                f32x4 v = acc[m][n] + other;
#pragma unroll
                for (int r = 0; r < 4; r++) {
                    C[(size_t)(rbase + m * 16 + r) * NDIM + cbase + n * 16] = v[r];
                }
            }
        }
    }
#undef STAGE
#undef COMPUTE
}

// ---------------------------------------------------------------------------
// Fallback (only if ws too small): textbook fp32 tiled GEMM with inline dequant
// ---------------------------------------------------------------------------
__global__ void fallback_kernel(const float* __restrict__ x,
                                const float* __restrict__ w0,
                                const int* __restrict__ nf4_idx,
                                const float* __restrict__ sp,
                                const float* __restrict__ zpp,
                                float* __restrict__ out)
{
    __shared__ float As[16][16], Bs[16][17];
    const int tx = threadIdx.x, ty = threadIdx.y;
    const int n0 = blockIdx.x * 16, m0 = blockIdx.y * 16;
    const float s = sp[0], zp = zpp[0];
    float acc = 0.0f;
    for (int k0 = 0; k0 < KDIM; k0 += 16) {
        As[ty][tx] = x[(size_t)(m0 + ty) * KDIM + k0 + tx];
        int id = nf4_idx[(size_t)(n0 + ty) * KDIM + k0 + tx];
        Bs[ty][tx] = w0[(size_t)(n0 + ty) * KDIM + k0 + tx] + c_nf4[id] * s + zp;
        __syncthreads();
#pragma unroll
        for (int j = 0; j < 16; j++) acc += As[ty][j] * Bs[tx][j];
        __syncthreads();
    }
    out[(size_t)(m0 + ty) * NDIM + n0 + tx] = acc;
}

extern "C" void kernel_launch(void* const* d_in, const int* in_sizes, int n_in,
                              void* d_out, int out_size, void* d_ws, size_t ws_size,
                              hipStream_t stream) {
    const float* x = (const float*)d_in[0];
    const float* w0 = (const float*)d_in[1];
    const int* nf4_idx = (const int*)d_in[2];
    const float* scale = (const float*)d_in[3];
    const float* zp = (const float*)d_in[4];
    float* out = (float*)d_out;

    const size_t wc_bytes = (size_t)NDIM * KDIM * 2;       // 33,554,432
    const size_t xb_bytes = (size_t)MDIM * KDIM * 2;       //  8,388,608

    if (ws_size >= wc_bytes + xb_bytes) {
        __hip_bfloat16* Wc = (__hip_bfloat16*)d_ws;
        __hip_bfloat16* xb = (__hip_bfloat16*)((char*)d_ws + wc_bytes);
        prep_kernel<<<W_BLOCKS + X_BLOCKS, 256, 0, stream>>>(
            x, w0, nf4_idx, scale, zp, Wc, xb);
        gemm_kernel<<<(MDIM / BM) * (NDIM / BN), 512, 0, stream>>>(xb, Wc, out);
    } else {
        fallback_kernel<<<dim3(NDIM / 16, MDIM / 16), dim3(16, 16), 0, stream>>>(
            x, w0, nf4_idx, scale, zp, out);
    }
}